// Round 4
// baseline (125.473 us; speedup 1.0000x reference)
//
#include <hip/hip_runtime.h>
#include <math.h>
#include <float.h>

#define N_RINGS  10
#define N_ANGLES 36
#define NP       360                 // points per batch
#define PI_APPROX 3.1415926f

#define BLOCK  256        // 4 waves
#define WPB    4
#define CHUNK  1024       // targets staged per block
#define PPT    6          // point-slots per lane: 6*64 = 384 >= 360

typedef float v2f __attribute__((ext_vector_type(2)));
typedef unsigned long long ull;

// One kernel does everything:
//  phase 1: per-(batch,chunk) block computes per-point min over its 1024
//           targets (paired-SoA LDS, v_pk_fma_f32 inner loop), stores the
//           clamped partial row to part[b][chunk][0..360) (coalesced).
//  phase 2: last block of each batch (per-batch counter) min-combines the
//           16 rows, double-sums its 360 mins, and adds ONE packed atomic:
//           (1<<56 arrival) | (sum * 2^30 fixed-point). The block that sees
//           arrivals==B-1 in the returned old value writes out[0].
//           Single atomic => arrival count and sum are mutually consistent;
//           fixed-point => bitwise-deterministic result.
__global__ __launch_bounds__(BLOCK) void chamfer_fused(
    const float* __restrict__ pred,    // B x N_RINGS
    const float* __restrict__ target,  // B x N x 3
    float* __restrict__ part,          // B x chunks x NP
    ull*  __restrict__ acc,            // packed accumulator (memset 0)
    unsigned int* __restrict__ bcnt,   // B arrival counters (memset 0)
    float* __restrict__ out,
    int N, int chunks, int B)
{
    __shared__ v2f   tp[CHUNK / 2][4];   // {x0,x1},{y0,y1},{z0,z1},{w0,w1}
    __shared__ float pm[WPB * NP];
    __shared__ float cs_c[N_ANGLES], cs_s[N_ANGLES];
    __shared__ double sd[WPB];
    __shared__ int   sh_last;

    const int b   = blockIdx.x / chunks;
    const int cg  = blockIdx.x % chunks;
    const int n0  = cg * CHUNK;
    const int tid = threadIdx.x;
    const int cnt = min(CHUNK, N - n0);
    const int cntp = (cnt + 1) & ~1;     // pad to even (duplicate last tgt)

    if (tid < N_ANGLES) {
        float angf = (float)(10 * tid) * (2.0f * PI_APPROX / 360.0f);
        double ang = (double)angf;
        cs_c[tid] = (float)cos(ang);
        cs_s[tid] = (float)sin(ang);
    }
    // stage targets, paired SoA: pair j = targets (2j, 2j+1)
    for (int i = tid; i < cntp; i += BLOCK) {
        int ii = min(i, cnt - 1);
        const float* t = target + ((size_t)b * N + (size_t)(n0 + ii)) * 3;
        float x = t[0], y = t[1], z = t[2];
        int j = i >> 1, h = i & 1;
        tp[j][0][h] = x;
        tp[j][1][h] = y;
        tp[j][2][h] = z;
        tp[j][3][h] = x * x + y * y + z * z;
    }
    __syncthreads();

    const int lane = tid & 63;
    const int w    = tid >> 6;

    // point setup: q = -2*p so d2-pp2 = fma(qz,z, fma(qy,y, fma(qx,x, |t|^2)))
    float qx[PPT], qy[PPT], qz[PPT], pp2[PPT], m[PPT];
    #pragma unroll
    for (int k = 0; k < PPT; ++k) {
        int s = lane + 64 * k;
        int j = s / N_ANGLES;
        int a = s - j * N_ANGLES;
        int jc = (j < N_RINGS) ? j : (N_RINGS - 1);   // clamp dummy slots
        float r  = pred[b * N_RINGS + jc];
        float px = -r * cs_c[a] + 0.04f;
        float py = 0.15f * (float)jc - 0.7f;
        float pz = r * cs_s[a];
        pp2[k] = px * px + py * py + pz * pz;
        qx[k] = -2.0f * px;
        qy[k] = -2.0f * py;
        qz[k] = -2.0f * pz;
        m[k]  = FLT_MAX;
    }

    // waves split the pairs; tp[k] wave-uniform -> broadcast ds_read_b128 x2.
    // v2f math + default -ffp-contract=fast -> v_pk_fma_f32.
    const int pairs = cntp >> 1;
    #pragma unroll 2
    for (int k = w; k < pairs; k += WPB) {
        v2f xv = tp[k][0], yv = tp[k][1], zv = tp[k][2], wv = tp[k][3];
        #pragma unroll
        for (int i = 0; i < PPT; ++i) {
            v2f h = qz[i] * zv + wv;
            h = qy[i] * yv + h;
            h = qx[i] * xv + h;
            m[i] = fminf(m[i], fminf(h.x, h.y));
        }
    }

    // finalize (add pp2, clamp) and publish per-wave partials
    #pragma unroll
    for (int k = 0; k < PPT; ++k) {
        int s = lane + 64 * k;
        if (s < NP) pm[w * NP + s] = fmaxf(pp2[k] + m[k], 0.0f);
    }
    __syncthreads();

    // cross-wave min, coalesced store of this block's partial row
    for (int p = tid; p < NP; p += BLOCK) {
        float v = fminf(fminf(pm[p], pm[NP + p]),
                        fminf(pm[2 * NP + p], pm[3 * NP + p]));
        part[((size_t)b * chunks + cg) * NP + p] = v;
    }
    __threadfence();          // release our row device-wide
    __syncthreads();
    if (tid == 0) {
        unsigned int old = atomicAdd(&bcnt[b], 1u);
        sh_last = (old == (unsigned int)(chunks - 1));
    }
    __syncthreads();
    if (!sh_last) return;

    // ---- phase 2: last block of batch b ----
    __threadfence();          // acquire other blocks' rows
    double lsum = 0.0;
    const float* pb = part + (size_t)b * chunks * NP;
    for (int p = tid; p < NP; p += BLOCK) {
        float mn = pb[p];
        for (int c = 1; c < chunks; ++c)
            mn = fminf(mn, pb[(size_t)c * NP + p]);
        lsum += (double)mn;
    }
    #pragma unroll
    for (int off = 32; off > 0; off >>= 1)
        lsum += __shfl_down(lsum, off, 64);
    if ((tid & 63) == 0) sd[tid >> 6] = lsum;
    __syncthreads();
    if (tid == 0) {
        double tot = sd[0] + sd[1] + sd[2] + sd[3];
        ull fx   = (ull)(tot * 1073741824.0);        // 2^30 fixed-point
        ull pack = fx | (1ULL << 56);                // +1 arrival
        ull old  = atomicAdd(acc, pack);
        if ((old >> 56) == (ull)(B - 1)) {           // I'm the global last
            ull tfx = (old + pack) & ((1ULL << 56) - 1ULL);
            out[0] = (float)((double)tfx / 1073741824.0 / (double)(B * NP));
        }
    }
}

extern "C" void kernel_launch(void* const* d_in, const int* in_sizes, int n_in,
                              void* d_out, int out_size, void* d_ws, size_t ws_size,
                              hipStream_t stream) {
    const float* pred   = (const float*)d_in[0];
    const float* target = (const float*)d_in[1];
    // d_in[2] (trans_feat) unused by the reference.

    const int B = in_sizes[0] / N_RINGS;
    const int N = in_sizes[1] / (3 * B);
    const int chunks = (N + CHUNK - 1) / CHUNK;     // 16 for N=16384

    float* part = (float*)d_ws;
    size_t partBytes = (size_t)B * chunks * NP * sizeof(float);  // 737,280 B
    ull* acc = (ull*)((char*)d_ws + partBytes);                  // 8-aligned
    unsigned int* bcnt = (unsigned int*)((char*)d_ws + partBytes + sizeof(ull));
    float* out = (float*)d_out;

    // zero only the counters + packed accumulator (136 B)
    hipMemsetAsync((char*)d_ws + partBytes, 0,
                   sizeof(ull) + (size_t)B * sizeof(unsigned int), stream);

    hipLaunchKernelGGL(chamfer_fused, dim3(B * chunks), dim3(BLOCK), 0, stream,
                       pred, target, part, acc, bcnt, out, N, chunks, B);
}

// Round 5
// 90.599 us; speedup vs baseline: 1.3849x; 1.3849x over previous
//
#include <hip/hip_runtime.h>
#include <math.h>
#include <float.h>

#define N_RINGS  10
#define N_ANGLES 36
#define NP       360                  // points per batch
#define PI_APPROX 3.1415926f

#define BLOCK  256        // 4 waves
#define WPB    4
#define CHUNK  512        // targets staged per block -> 1024 blocks, 4 waves/SIMD
#define PPT    6          // point-slots per lane: 6*64 = 384 >= 360

// ---------------- kernel A: per-(batch, target-chunk) block --------------
// Each lane owns 6 point slots (l, l+64, ..., l+320). Waves split the staged
// CHUNK of targets; each wave-uniform ds_read_b128 broadcast feeds 6 points
// (24 FMA + 6 MIN). Block stores its clamped partial row to
// part[b][chunk][0..360) with plain coalesced stores. NO fences/atomics —
// the kernel boundary provides cross-XCD coherence for kernel B.
__global__ __launch_bounds__(BLOCK) void chamfer_partial(
    const float* __restrict__ pred,    // B x N_RINGS
    const float* __restrict__ target,  // B x N x 3
    float* __restrict__ part,          // B x chunks x NP
    int N, int chunks)
{
    __shared__ float4 t4[CHUNK];          // x, y, z, |t|^2
    __shared__ float  pm[WPB * NP];       // per-wave clamped partial mins
    __shared__ float  cs_c[N_ANGLES], cs_s[N_ANGLES];

    const int b   = blockIdx.x / chunks;
    const int cg  = blockIdx.x % chunks;
    const int n0  = cg * CHUNK;
    const int tid = threadIdx.x;
    const int cnt = min(CHUNK, N - n0);

    if (tid < N_ANGLES) {
        float angf = (float)(10 * tid) * (2.0f * PI_APPROX / 360.0f);
        double ang = (double)angf;
        cs_c[tid] = (float)cos(ang);
        cs_s[tid] = (float)sin(ang);
    }
    // stage target chunk: x, y, z, |t|^2
    for (int i = tid; i < cnt; i += BLOCK) {
        const float* t = target + ((size_t)b * N + (size_t)(n0 + i)) * 3;
        float x = t[0], y = t[1], z = t[2];
        t4[i] = make_float4(x, y, z, x * x + y * y + z * z);
    }
    __syncthreads();

    const int lane = tid & 63;
    const int w    = tid >> 6;

    // q = -2*p so d2 - pp2 = fma(qz,z, fma(qy,y, fma(qx,x, |t|^2)))
    float qx[PPT], qy[PPT], qz[PPT], pp2[PPT], m[PPT];
    #pragma unroll
    for (int k = 0; k < PPT; ++k) {
        int s = lane + 64 * k;
        int j = s / N_ANGLES;
        int a = s - j * N_ANGLES;
        int jc = (j < N_RINGS) ? j : (N_RINGS - 1);   // clamp dummy slots
        float r  = pred[b * N_RINGS + jc];
        float px = -r * cs_c[a] + 0.04f;
        float py = 0.15f * (float)jc - 0.7f;
        float pz = r * cs_s[a];
        pp2[k] = px * px + py * py + pz * pz;
        qx[k] = -2.0f * px;
        qy[k] = -2.0f * py;
        qz[k] = -2.0f * pz;
        m[k]  = FLT_MAX;
    }

    // waves split the chunk; t4[k] is wave-uniform -> broadcast ds_read_b128
    #pragma unroll 4
    for (int k = w; k < cnt; k += WPB) {
        float4 t = t4[k];
        #pragma unroll
        for (int i = 0; i < PPT; ++i) {
            float h = fmaf(qz[i], t.z, t.w);
            h = fmaf(qy[i], t.y, h);
            h = fmaf(qx[i], t.x, h);
            m[i] = fminf(m[i], h);
        }
    }

    // finalize (add pp2, clamp) and publish per-wave partials
    #pragma unroll
    for (int k = 0; k < PPT; ++k) {
        int s = lane + 64 * k;
        if (s < NP) pm[w * NP + s] = fmaxf(pp2[k] + m[k], 0.0f);
    }
    __syncthreads();

    // cross-wave min, coalesced store of this block's partial row
    for (int p = tid; p < NP; p += BLOCK) {
        float v = fminf(fminf(pm[p], pm[NP + p]),
                        fminf(pm[2 * NP + p], pm[3 * NP + p]));
        part[((size_t)b * chunks + cg) * NP + p] = v;
    }
}

// ---------------- kernel B: one block per batch ---------------------------
// Min over the batch's chunk rows (coalesced, L2-warm), double block-sum.
__global__ __launch_bounds__(BLOCK) void batch_sum(
    const float* __restrict__ part, double* __restrict__ ws2,
    int chunks)
{
    __shared__ double sd[WPB];
    const int b   = blockIdx.x;
    const int tid = threadIdx.x;
    const float* pb = part + (size_t)b * chunks * NP;

    double s = 0.0;
    for (int p = tid; p < NP; p += BLOCK) {
        float mn = pb[p];
        for (int c = 1; c < chunks; ++c)
            mn = fminf(mn, pb[(size_t)c * NP + p]);
        s += (double)mn;
    }
    #pragma unroll
    for (int off = 32; off > 0; off >>= 1)
        s += __shfl_down(s, off, 64);
    if ((tid & 63) == 0) sd[tid >> 6] = s;
    __syncthreads();
    if (tid == 0)
        ws2[b] = sd[0] + sd[1] + sd[2] + sd[3];
}

// ---------------- kernel C: final mean ------------------------------------
__global__ __launch_bounds__(64) void final_mean(
    const double* __restrict__ ws2, float* __restrict__ out, int B)
{
    const int tid = threadIdx.x;
    double s = (tid < B) ? ws2[tid] : 0.0;
    #pragma unroll
    for (int off = 32; off > 0; off >>= 1)
        s += __shfl_down(s, off, 64);
    if (tid == 0)
        out[0] = (float)(s / (double)(B * NP));
}

extern "C" void kernel_launch(void* const* d_in, const int* in_sizes, int n_in,
                              void* d_out, int out_size, void* d_ws, size_t ws_size,
                              hipStream_t stream) {
    const float* pred   = (const float*)d_in[0];
    const float* target = (const float*)d_in[1];
    // d_in[2] (trans_feat) unused by the reference.

    const int B = in_sizes[0] / N_RINGS;
    const int N = in_sizes[1] / (3 * B);
    const int chunks = (N + CHUNK - 1) / CHUNK;     // 32 for N=16384

    float* part = (float*)d_ws;
    size_t partBytes = (size_t)B * chunks * NP * sizeof(float);  // 1.47 MB
    double* ws2 = (double*)((char*)d_ws + partBytes);            // 8-aligned
    float* out = (float*)d_out;

    hipLaunchKernelGGL(chamfer_partial, dim3(B * chunks), dim3(BLOCK), 0, stream,
                       pred, target, part, N, chunks);
    hipLaunchKernelGGL(batch_sum, dim3(B), dim3(BLOCK), 0, stream,
                       part, ws2, chunks);
    hipLaunchKernelGGL(final_mean, dim3(1), dim3(64), 0, stream,
                       ws2, out, B);
}

// Round 6
// 86.762 us; speedup vs baseline: 1.4462x; 1.0442x over previous
//
#include <hip/hip_runtime.h>
#include <math.h>
#include <float.h>

#define N_RINGS  10
#define N_ANGLES 36
#define NP       360                  // points per batch
#define PI_APPROX 3.1415926f

#define BLOCK  256        // 4 waves
#define WPB    4
#define CHUNK  1024       // targets staged per block -> 512 blocks
#define PPT    6          // point-slots per lane: 6*64 = 384 >= 360

typedef float v2f __attribute__((ext_vector_type(2)));

// ---------------- kernel A: per-(batch, target-chunk) block --------------
// R4's verified-fast phase 1, fence-free tail. Each lane owns 6 point slots;
// targets staged as paired SoA {x0,x1}{y0,y1}{z0,z1}{w0,w1} so the inner
// loop is 3 v_pk_fma_f32 + 1 v_min3_f32 per 2 targets per point. Block
// stores its clamped partial row to part[b][chunk][0..360) with plain
// coalesced stores — kernel boundary provides cross-XCD coherence.
__global__ __launch_bounds__(BLOCK) void chamfer_partial(
    const float* __restrict__ pred,    // B x N_RINGS
    const float* __restrict__ target,  // B x N x 3
    float* __restrict__ part,          // B x chunks x NP
    int N, int chunks)
{
    __shared__ v2f   tp[CHUNK / 2][4];    // {x0,x1},{y0,y1},{z0,z1},{w0,w1}
    __shared__ float pm[WPB * NP];        // per-wave clamped partial mins
    __shared__ float cs_c[N_ANGLES], cs_s[N_ANGLES];

    const int b   = blockIdx.x / chunks;
    const int cg  = blockIdx.x % chunks;
    const int n0  = cg * CHUNK;
    const int tid = threadIdx.x;
    const int cnt = min(CHUNK, N - n0);
    const int cntp = (cnt + 1) & ~1;      // pad to even (dup last target)

    if (tid < N_ANGLES) {
        float angf = (float)(10 * tid) * (2.0f * PI_APPROX / 360.0f);
        double ang = (double)angf;
        cs_c[tid] = (float)cos(ang);
        cs_s[tid] = (float)sin(ang);
    }
    // stage targets, paired SoA: pair j = targets (2j, 2j+1)
    for (int i = tid; i < cntp; i += BLOCK) {
        int ii = min(i, cnt - 1);
        const float* t = target + ((size_t)b * N + (size_t)(n0 + ii)) * 3;
        float x = t[0], y = t[1], z = t[2];
        int j = i >> 1, h = i & 1;
        tp[j][0][h] = x;
        tp[j][1][h] = y;
        tp[j][2][h] = z;
        tp[j][3][h] = x * x + y * y + z * z;
    }
    __syncthreads();

    const int lane = tid & 63;
    const int w    = tid >> 6;

    // q = -2*p so d2 - pp2 = fma(qz,z, fma(qy,y, fma(qx,x, |t|^2)))
    float qx[PPT], qy[PPT], qz[PPT], pp2[PPT], m[PPT];
    #pragma unroll
    for (int k = 0; k < PPT; ++k) {
        int s = lane + 64 * k;
        int j = s / N_ANGLES;
        int a = s - j * N_ANGLES;
        int jc = (j < N_RINGS) ? j : (N_RINGS - 1);   // clamp dummy slots
        float r  = pred[b * N_RINGS + jc];
        float px = -r * cs_c[a] + 0.04f;
        float py = 0.15f * (float)jc - 0.7f;
        float pz = r * cs_s[a];
        pp2[k] = px * px + py * py + pz * pz;
        qx[k] = -2.0f * px;
        qy[k] = -2.0f * py;
        qz[k] = -2.0f * pz;
        m[k]  = FLT_MAX;
    }

    // waves split the pairs; tp[k] wave-uniform -> 2x broadcast ds_read_b128
    const int pairs = cntp >> 1;
    #pragma unroll 2
    for (int k = w; k < pairs; k += WPB) {
        v2f xv = tp[k][0], yv = tp[k][1], zv = tp[k][2], wv = tp[k][3];
        #pragma unroll
        for (int i = 0; i < PPT; ++i) {
            v2f h = qz[i] * zv + wv;      // v_pk_fma_f32
            h = qy[i] * yv + h;
            h = qx[i] * xv + h;
            m[i] = fminf(m[i], fminf(h.x, h.y));   // v_min3_f32
        }
    }

    // finalize (add pp2, clamp) and publish per-wave partials
    #pragma unroll
    for (int k = 0; k < PPT; ++k) {
        int s = lane + 64 * k;
        if (s < NP) pm[w * NP + s] = fmaxf(pp2[k] + m[k], 0.0f);
    }
    __syncthreads();

    // cross-wave min, coalesced store of this block's partial row
    for (int p = tid; p < NP; p += BLOCK) {
        float v = fminf(fminf(pm[p], pm[NP + p]),
                        fminf(pm[2 * NP + p], pm[3 * NP + p]));
        part[((size_t)b * chunks + cg) * NP + p] = v;
    }
}

// ---------------- kernel B: one block per batch ---------------------------
// Min over the batch's chunk rows (coalesced, L2-warm), double block-sum.
__global__ __launch_bounds__(BLOCK) void batch_sum(
    const float* __restrict__ part, double* __restrict__ ws2,
    int chunks)
{
    __shared__ double sd[WPB];
    const int b   = blockIdx.x;
    const int tid = threadIdx.x;
    const float* pb = part + (size_t)b * chunks * NP;

    double s = 0.0;
    for (int p = tid; p < NP; p += BLOCK) {
        float mn = pb[p];
        for (int c = 1; c < chunks; ++c)
            mn = fminf(mn, pb[(size_t)c * NP + p]);
        s += (double)mn;
    }
    #pragma unroll
    for (int off = 32; off > 0; off >>= 1)
        s += __shfl_down(s, off, 64);
    if ((tid & 63) == 0) sd[tid >> 6] = s;
    __syncthreads();
    if (tid == 0)
        ws2[b] = sd[0] + sd[1] + sd[2] + sd[3];
}

// ---------------- kernel C: final mean ------------------------------------
__global__ __launch_bounds__(64) void final_mean(
    const double* __restrict__ ws2, float* __restrict__ out, int B)
{
    const int tid = threadIdx.x;
    double s = (tid < B) ? ws2[tid] : 0.0;
    #pragma unroll
    for (int off = 32; off > 0; off >>= 1)
        s += __shfl_down(s, off, 64);
    if (tid == 0)
        out[0] = (float)(s / (double)(B * NP));
}

extern "C" void kernel_launch(void* const* d_in, const int* in_sizes, int n_in,
                              void* d_out, int out_size, void* d_ws, size_t ws_size,
                              hipStream_t stream) {
    const float* pred   = (const float*)d_in[0];
    const float* target = (const float*)d_in[1];
    // d_in[2] (trans_feat) unused by the reference.

    const int B = in_sizes[0] / N_RINGS;
    const int N = in_sizes[1] / (3 * B);
    const int chunks = (N + CHUNK - 1) / CHUNK;     // 16 for N=16384

    float* part = (float*)d_ws;
    size_t partBytes = (size_t)B * chunks * NP * sizeof(float);  // 737 KB
    double* ws2 = (double*)((char*)d_ws + partBytes);            // 8-aligned
    float* out = (float*)d_out;

    hipLaunchKernelGGL(chamfer_partial, dim3(B * chunks), dim3(BLOCK), 0, stream,
                       pred, target, part, N, chunks);
    hipLaunchKernelGGL(batch_sum, dim3(B), dim3(BLOCK), 0, stream,
                       part, ws2, chunks);
    hipLaunchKernelGGL(final_mean, dim3(1), dim3(64), 0, stream,
                       ws2, out, B);
}